// Round 4
// baseline (359.306 us; speedup 1.0000x reference)
//
#include <hip/hip_runtime.h>
#include <math.h>

// ---------------------------------------------------------------------------
// Decoder block: x -> QKV proj -> causal MHA -> a + LN(a) -> FFN -> f + LN(f)
// B=2 T=2048 C=1024 NH=16 hd=64 DFF=4096, fp32 in/out.
// Round 18:
//   * R17 (2-phase dbuf + __syncthreads) was NULL: any loop ending in a
//     vmcnt(0) drain has the same ~23% MfmaUtil ceiling (m99/m100/m230).
//     MFMA 23% + VALU 24% -> 53% of cycles are the synchronized drain.
//   * Fix = T4 counted vmcnt: tri-buffered LDS pipeline (stage k+2 each
//     iter), raw s_barrier + "s_waitcnt vmcnt(L)" (L = loads/stage/wave),
//     so the newest stage batch stays in flight ACROSS the barrier and
//     every load gets a ~2-K-step completion window. vmcnt(0) only in the
//     peeled final iteration.
//   * Race proof: compute(t) reads buf staged at t-2 (vmcnt(L) oldest-first
//     + barrier); stage(t+2) overwrites buf computed at t-1 (freed by the
//     same barrier; ds_reads consumed before MFMAs issue).
//   * Tiles unchanged: dual <64,64,2> (48 KB), FFN1 <64,128,2> (72 KB),
//     FFN2 <128,64,2> + XCD swizzle (72 KB). fattn/prep/add_ln untouched.
// ---------------------------------------------------------------------------

typedef __attribute__((ext_vector_type(8))) short short8;
typedef __attribute__((ext_vector_type(4))) float f32x4;

__device__ __forceinline__ unsigned short f2bf(float f) {
    unsigned u = __builtin_bit_cast(unsigned, f);
    unsigned r = u + 0x7fffu + ((u >> 16) & 1u);   // RNE
    return (unsigned short)(r >> 16);
}

// ---------------------------------------------------------------------------
// Merged preprocessing. Grid = 15368 blocks of 256.
// ---------------------------------------------------------------------------
__global__ __launch_bounds__(256) void prep_kernel(
    const float* __restrict__ x,  const float* __restrict__ Wq,
    const float* __restrict__ Wk, const float* __restrict__ Wv,
    const float* __restrict__ W1, const float* __restrict__ W2,
    const float* __restrict__ bq, const float* __restrict__ bk,
    unsigned short* __restrict__ x_bf,  unsigned short* __restrict__ Wqk_t,
    unsigned short* __restrict__ Wvt,   unsigned short* __restrict__ W1t,
    unsigned short* __restrict__ W2t,   float* __restrict__ bqk)
{
    const int bid = blockIdx.x;
    const int tid = threadIdx.x;

    if (bid < 4096) {                       // x convert
        const int i = (bid * 256 + tid) * 4;
        float4 v = *(const float4*)(x + i);
        ushort4 o;
        o.x = f2bf(v.x); o.y = f2bf(v.y); o.z = f2bf(v.z); o.w = f2bf(v.w);
        *(ushort4*)(x_bf + i) = o;
        return;
    }
    if (bid >= 15360) {                     // bias concat
        const int i = (bid - 15360) * 256 + tid;
        bqk[i] = i < 1024 ? bq[i] : bk[i - 1024];
        return;
    }

    __shared__ float tile[32][33];
    const float* src; unsigned short* dst; int K, N, t;
    if (bid < 5120)       { t = bid - 4096;  src = Wq; dst = Wqk_t;            K = 1024; N = 1024; }
    else if (bid < 6144)  { t = bid - 5120;  src = Wk; dst = Wqk_t + 1048576;  K = 1024; N = 1024; }
    else if (bid < 7168)  { t = bid - 6144;  src = Wv; dst = Wvt;              K = 1024; N = 1024; }
    else if (bid < 11264) { t = bid - 7168;  src = W1; dst = W1t;              K = 1024; N = 4096; }
    else                  { t = bid - 11264; src = W2; dst = W2t;              K = 4096; N = 1024; }

    const int ncols = N >> 5;
    const int n0 = (t % ncols) * 32;
    const int k0 = (t / ncols) * 32;
    const int tx = tid & 31;
    const int ty = tid >> 5;                // 0..7
#pragma unroll
    for (int i = 0; i < 4; ++i)
        tile[ty + i * 8][tx] = src[(size_t)(k0 + ty + i * 8) * N + n0 + tx];
    __syncthreads();
#pragma unroll
    for (int i = 0; i < 4; ++i)
        dst[(size_t)(n0 + ty + i * 8) * K + k0 + tx] = f2bf(tile[tx][ty + i * 8]);
}

// ---------------------------------------------------------------------------
// GEMM body, 3-deep pipelined: C[M][N] = A[M][K] . Bt[N][K]^T + bias.
// TMxTN tile at (bx, by), NP 32-wide LDS planes per buffer, 3 buffers.
// Per K-step: vmcnt(L) [oldest stage done, newest in flight] -> s_barrier ->
// stage(k+2) -> compute(cur) -> rotate. vmcnt(0) only in the peeled tail.
// mode: 0 = fp32 out, bias[col]; 1 = relu->bf16, bias[col];
//       2 = bf16, bias[col];     3 = bf16, bias[row].
// ---------------------------------------------------------------------------
template <int TM, int TN, int NP>
__device__ __forceinline__ void gemm_body(
    unsigned short* As, unsigned short* Bs,   // each holds 3 buffers
    const unsigned short* __restrict__ A, const unsigned short* __restrict__ Bt,
    const float* __restrict__ bias, float* __restrict__ Cf,
    unsigned short* __restrict__ Cb, int M, int N, int K, int mode,
    int bx, int by)
{
    constexpr int NI   = TM / 32;
    constexpr int NJ   = TN / 32;
    constexpr int NCA  = TM / 16;
    constexpr int NCB  = TN / 16;
    constexpr int MAXA = (NCA + 3) / 4;
    constexpr int MAXB = (NCB + 3) / 4;
    constexpr int ASZ  = NP * TM * 32;
    constexpr int BSZ  = NP * TN * 32;
    constexpr int STEP = NP * 32;
    constexpr int LPW  = NP * (NCA + NCB) / 4;   // loads per wave per stage

    const int tid  = threadIdx.x;
    const int lane = tid & 63;
    const int w    = tid >> 6;
    const int wm   = (w & 1) * (TM / 2);
    const int wn   = (w >> 1) * (TN / 2);
    const int fm   = lane & 15;
    const int quad = lane >> 4;

    const int row0 = by * TM;
    const int col0 = bx * TN;

    const int srow = lane >> 2;
    const int scol = (lane & 3) * 8;

    const unsigned short* aptr[MAXA];
    int aoff[MAXA];
#pragma unroll
    for (int i = 0; i < MAXA; ++i) {
        const int c = w + i * 4;
        if (c < NCA) {
            aptr[i] = A + (size_t)(row0 + c * 16 + srow) * K + scol;
            aoff[i] = c * 16 * 32;
        }
    }
    const unsigned short* bptr[MAXB];
    int boff[MAXB];
#pragma unroll
    for (int i = 0; i < MAXB; ++i) {
        const int c = w + i * 4;
        if (c < NCB) {
            bptr[i] = Bt + (size_t)(col0 + c * 16 + srow) * K + scol;
            boff[i] = c * 16 * 32;
        }
    }

    // Stage NP planes of the A-tile + B-tile at K offset k0 into Ab/Bb.
    auto stage = [&](int k0, unsigned short* Ab, unsigned short* Bb) {
#pragma unroll
        for (int p = 0; p < NP; ++p) {
#pragma unroll
            for (int i = 0; i < MAXA; ++i)
                if (w + i * 4 < NCA)          // wave-uniform
                    __builtin_amdgcn_global_load_lds(
                        (const __attribute__((address_space(1))) void*)(aptr[i] + k0 + p * 32),
                        (__attribute__((address_space(3))) void*)&Ab[p * TM * 32 + aoff[i]], 16, 0, 0);
#pragma unroll
            for (int i = 0; i < MAXB; ++i)
                if (w + i * 4 < NCB)          // wave-uniform
                    __builtin_amdgcn_global_load_lds(
                        (const __attribute__((address_space(1))) void*)(bptr[i] + k0 + p * 32),
                        (__attribute__((address_space(3))) void*)&Bb[p * TN * 32 + boff[i]], 16, 0, 0);
        }
    };

    f32x4 acc[NI][NJ] = {};

    auto compute = [&](unsigned short* Ac, unsigned short* Bc) {
#pragma unroll
        for (int p = 0; p < NP; ++p) {
            short8 af[NI], bf[NJ];
#pragma unroll
            for (int i = 0; i < NI; ++i)
                af[i] = *(const short8*)&Ac[p * TM * 32 + (wm + i * 16 + fm) * 32 + quad * 8];
#pragma unroll
            for (int j = 0; j < NJ; ++j)
                bf[j] = *(const short8*)&Bc[p * TN * 32 + (wn + j * 16 + fm) * 32 + quad * 8];
#pragma unroll
            for (int i = 0; i < NI; ++i)
#pragma unroll
                for (int j = 0; j < NJ; ++j)
                    acc[i][j] = __builtin_amdgcn_mfma_f32_16x16x32_bf16(
                        af[i], bf[j], acc[i][j], 0, 0, 0);
        }
    };

    unsigned short *A0 = As, *A1 = As + ASZ, *A2 = As + 2 * ASZ;
    unsigned short *B0 = Bs, *B1 = Bs + BSZ, *B2 = Bs + 2 * BSZ;

    // Prologue: fill pipeline 2 deep (K >= 2*STEP in all uses).
    stage(0, A0, B0);
    stage(STEP, A1, B1);

    const int TSTEPS = K / STEP;
    for (int t = 0; t < TSTEPS - 1; ++t) {
        // Oldest stage (-> current buffer) complete; newest may stay in flight.
        asm volatile("s_waitcnt vmcnt(%0)" :: "n"(LPW) : "memory");
        __builtin_amdgcn_s_barrier();
        const int k2 = (t + 2) * STEP;
        if (k2 < K) stage(k2, A2, B2);       // wave-uniform guard
        compute(A0, B0);
        unsigned short* r;
        r = A0; A0 = A1; A1 = A2; A2 = r;
        r = B0; B0 = B1; B1 = B2; B2 = r;
    }
    // Peeled final step: full drain (only place vmcnt reaches 0).
    asm volatile("s_waitcnt vmcnt(0)" ::: "memory");
    __builtin_amdgcn_s_barrier();
    compute(A0, B0);

    // Epilogue. C/D layout: col = lane&15, row = quad*4 + reg.
#pragma unroll
    for (int j = 0; j < NJ; ++j) {
        const int col = col0 + wn + j * 16 + fm;
        const float bcol = (mode == 3) ? 0.f : bias[col];
#pragma unroll
        for (int i = 0; i < NI; ++i) {
            const int rbase = row0 + wm + i * 16 + quad * 4;
#pragma unroll
            for (int r = 0; r < 4; ++r) {
                const int row = rbase + r;
                float val = acc[i][j][r] + ((mode == 3) ? bias[row] : bcol);
                if (mode == 1) val = fmaxf(val, 0.f);
                if (mode == 0) Cf[(size_t)row * N + col] = val;
                else           Cb[(size_t)row * N + col] = f2bf(val);
            }
        }
    }
}

template <int TM, int TN, int NP>
__global__ __launch_bounds__(256) void gemm_bf16_mfma(
    const unsigned short* __restrict__ A, const unsigned short* __restrict__ Bt,
    const float* __restrict__ bias, float* __restrict__ Cf,
    unsigned short* __restrict__ Cb, int M, int N, int K, int mode)
{
    __shared__ unsigned short As[3 * NP * TM * 32];
    __shared__ unsigned short Bs[3 * NP * TN * 32];
    gemm_body<TM, TN, NP>(As, Bs, A, Bt, bias, Cf, Cb, M, N, K, mode,
                          blockIdx.x, blockIdx.y);
}

// Flat-grid GEMM with XCD-aware block swizzle: bid&7 = XCD (HW round-robin);
// each XCD gets a compact nx-col x rows_per_xcd-row region of the tile grid.
template <int TM, int TN, int NP>
__global__ __launch_bounds__(256) void gemm_xcd(
    const unsigned short* __restrict__ A, const unsigned short* __restrict__ Bt,
    const float* __restrict__ bias, float* __restrict__ Cf,
    unsigned short* __restrict__ Cb, int M, int N, int K, int mode,
    int nx, int rows_per_xcd)
{
    __shared__ unsigned short As[3 * NP * TM * 32];
    __shared__ unsigned short Bs[3 * NP * TN * 32];
    const int xcd = blockIdx.x & 7;
    const int idx = blockIdx.x >> 3;
    const int bx  = idx % nx;
    const int by  = xcd * rows_per_xcd + idx / nx;
    gemm_body<TM, TN, NP>(As, Bs, A, Bt, bias, Cf, Cb, M, N, K, mode, bx, by);
}

// Two independent GEMMs (same tile config) in one flat-grid dispatch.
template <int TM, int TN, int NP>
__global__ __launch_bounds__(256) void gemm_dual(
    const unsigned short* __restrict__ A0, const unsigned short* __restrict__ B0,
    const float* __restrict__ bias0, unsigned short* __restrict__ C0,
    int M0, int N0, int K0, int mode0, int nb0, int nx0,
    const unsigned short* __restrict__ A1, const unsigned short* __restrict__ B1,
    const float* __restrict__ bias1, unsigned short* __restrict__ C1,
    int M1, int N1, int K1, int mode1, int nx1)
{
    __shared__ unsigned short As[3 * NP * TM * 32];
    __shared__ unsigned short Bs[3 * NP * TN * 32];
    const int bid = blockIdx.x;
    if (bid < nb0) {
        gemm_body<TM, TN, NP>(As, Bs, A0, B0, bias0, nullptr, C0,
                              M0, N0, K0, mode0, bid % nx0, bid / nx0);
    } else {
        const int t = bid - nb0;
        gemm_body<TM, TN, NP>(As, Bs, A1, B1, bias1, nullptr, C1,
                              M1, N1, K1, mode1, t % nx1, t / nx1);
    }
}

// ---------------------------------------------------------------------------
// MFMA flash attention v2. qk: [4096][2048] bf16 (q cols 0..1023, k 1024..),
// vt: [1024][4096] bf16 (row = h*64+d, col = b*2048+t), a: [4096][1024] fp32.
// ---------------------------------------------------------------------------
__global__ __launch_bounds__(256) void fattn_mfma(
    const unsigned short* __restrict__ qk,
    const unsigned short* __restrict__ vt,
    float* __restrict__ a)
{
    const int T = 2048, LDQK = 2048, LDVT = 4096, OUTC = 1024;
    const float cs = 0.04508422f;       // (1/32) * log2(e)

    __shared__ unsigned short Qs[2][64][32];
    __shared__ unsigned short Ks[2][64][32];
    __shared__ unsigned short Vs[2][64][32];
    __shared__ unsigned short Ps[4][16][72];

    const int tid  = threadIdx.x;
    const int lane = tid & 63;
    const int w    = tid >> 6;
    const int fm   = lane & 15;
    const int quad = lane >> 4;
    const int srow = lane >> 2;
    const int scol = (lane & 3) * 8;

    const int n  = blockIdx.x;
    const int lo = n & 255, hi = n >> 8;
    const int h  = ((lo >> 5) & 7) | ((hi & 1) << 3);
    const int b  = hi >> 1;
    const int qv = lo & 31;
    const int u  = ((qv & 1) << 4) | ((qv & 2) << 2) | (qv & 4) |
                   ((qv & 8) >> 2) | ((qv & 16) >> 4);
    const int qb = (hi & 1) ? (31 - u) : u;
    const int q0 = qb * 64;

    const size_t rowbase = (size_t)b * T;

#pragma unroll
    for (int i = 0; i < 2; ++i) {
        const int c  = w * 2 + i;
        const int kh = c & 1, rg = c >> 1;
        const unsigned short* src = qk + (rowbase + q0 + rg * 16 + srow) * LDQK
                                       + h * 64 + kh * 32 + scol;
        __builtin_amdgcn_global_load_lds(
            (const __attribute__((address_space(1))) void*)src,
            (__attribute__((address_space(3))) void*)&Qs[kh][rg * 16][0], 16, 0, 0);
    }
    __syncthreads();
    short8 qf0 = *(const short8*)&Qs[0][w * 16 + fm][quad * 8];
    short8 qf1 = *(const short8*)&Qs[1][w * 16 + fm][quad * 8];

    short8 ones;
#pragma unroll
    for (int i = 0; i < 8; ++i) ones[i] = (short)0x3F80;   // bf16 1.0

    f32x4 o[4] = {};
    f32x4 lacc = {};

    const int qglob = q0 + w * 16 + fm;

    for (int jt = 0; jt <= qb; ++jt) {
        const int j0 = jt * 64;
        __syncthreads();
#pragma unroll
        for (int i = 0; i < 2; ++i) {
            const int c  = w * 2 + i;
            const int kh = c & 1, rg = c >> 1;
            const unsigned short* ksrc = qk + (rowbase + j0 + rg * 16 + srow) * LDQK
                                            + 1024 + h * 64 + kh * 32 + scol;
            __builtin_amdgcn_global_load_lds(
                (const __attribute__((address_space(1))) void*)ksrc,
                (__attribute__((address_space(3))) void*)&Ks[kh][rg * 16][0], 16, 0, 0);
            const unsigned short* vsrc = vt + (size_t)(h * 64 + rg * 16 + srow) * LDVT
                                            + rowbase + j0 + kh * 32 + scol;
            __builtin_amdgcn_global_load_lds(
                (const __attribute__((address_space(1))) void*)vsrc,
                (__attribute__((address_space(3))) void*)&Vs[kh][rg * 16][0], 16, 0, 0);
        }
        __syncthreads();

        // S^T = K . Q^T
        f32x4 s[4];
#pragma unroll
        for (int j = 0; j < 4; ++j) {
            short8 k0 = *(const short8*)&Ks[0][j * 16 + fm][quad * 8];
            short8 k1 = *(const short8*)&Ks[1][j * 16 + fm][quad * 8];
            f32x4 acc = {};
            acc = __builtin_amdgcn_mfma_f32_16x16x32_bf16(k0, qf0, acc, 0, 0, 0);
            acc = __builtin_amdgcn_mfma_f32_16x16x32_bf16(k1, qf1, acc, 0, 0, 0);
            s[j] = acc;
        }

        if (jt == qb) {
#pragma unroll
            for (int j = 0; j < 4; ++j) {
                const int kbase = j0 + j * 16 + quad * 4;
#pragma unroll
                for (int r = 0; r < 4; ++r) {
                    const float e = exp2f(s[j][r] * cs);
                    s[j][r] = (kbase + r > qglob) ? 0.f : e;
                }
            }
        } else {
#pragma unroll
            for (int j = 0; j < 4; ++j)
#pragma unroll
                for (int r = 0; r < 4; ++r)
                    s[j][r] = exp2f(s[j][r] * cs);
        }

#pragma unroll
        for (int j = 0; j < 4; ++j) {
            const unsigned d0 = (unsigned)f2bf(s[j][0]) | ((unsigned)f2bf(s[j][1]) << 16);
            const unsigned d1 = (unsigned)f2bf(s[j][2]) | ((unsigned)f2bf(s[j][3]) << 16);
            *(uint2*)&Ps[w][fm][j * 16 + quad * 4] = make_uint2(d0, d1);
        }
        short8 pf0 = *(const short8*)&Ps[w][fm][quad * 8];
        short8 pf1 = *(const short8*)&Ps[w][fm][32 + quad * 8];

#pragma unroll
        for (int jd = 0; jd < 4; ++jd) {
            short8 v0 = *(const short8*)&Vs[0][jd * 16 + fm][quad * 8];
            short8 v1 = *(const short8*)&Vs[1][jd * 16 + fm][quad * 8];
            o[jd] = __builtin_amdgcn_mfma_f32_16x16x32_bf16(pf0, v0, o[jd], 0, 0, 0);
            o[jd] = __builtin_amdgcn_mfma_f32_16x16x32_bf16(pf1, v1, o[jd], 0, 0, 0);
        }
        lacc = __builtin_amdgcn_mfma_f32_16x16x32_bf16(pf0, ones, lacc, 0, 0, 0);
        lacc = __builtin_amdgcn_mfma_f32_16x16x32_bf16(pf1, ones, lacc, 0, 0, 0);
    }

    const size_t orow = rowbase + q0 + w * 16 + quad * 4;
#pragma unroll
    for (int r = 0; r < 4; ++r) {
        const float inv = 1.0f / lacc[r];
#pragma unroll
        for (int jd = 0; jd < 4; ++jd)
            a[(orow + r) * OUTC + h * 64 + jd * 16 + fm] = o[jd][r] * inv;
    }
}

// out = in + LayerNorm(in)*w. bf16_out=1 -> write bf16 to outb, else fp32 outf.
__global__ __launch_bounds__(256) void add_ln_kernel(
    const float* __restrict__ in, const float* __restrict__ w,
    float* __restrict__ outf, unsigned short* __restrict__ outb, int bf16_out)
{
    const int C = 1024;
    const int row = blockIdx.x;
    const int tid = threadIdx.x;

    __shared__ float red[256];

    const float* x = in + (size_t)row * C;
    float4 xv = *(const float4*)(x + tid * 4);

    red[tid] = xv.x + xv.y + xv.z + xv.w;
    __syncthreads();
    for (int off = 128; off > 0; off >>= 1) {
        if (tid < off) red[tid] += red[tid + off];
        __syncthreads();
    }
    const float mu = red[0] * (1.0f / 1024.0f);
    __syncthreads();

    float dx = xv.x - mu, dy = xv.y - mu, dz = xv.z - mu, dw = xv.w - mu;
    red[tid] = dx * dx + dy * dy + dz * dz + dw * dw;
    __syncthreads();
    for (int off = 128; off > 0; off >>= 1) {
        if (tid < off) red[tid] += red[tid + off];
        __syncthreads();
    }
    const float rstd = rsqrtf(red[0] * (1.0f / 1024.0f) + 1e-5f);

    float4 wv = *(const float4*)(w + tid * 4);
    float ox = xv.x + dx * rstd * wv.x;
    float oy = xv.y + dy * rstd * wv.y;
    float oz = xv.z + dz * rstd * wv.z;
    float ow = xv.w + dw * rstd * wv.w;
    if (bf16_out) {
        ushort4 o4;
        o4.x = f2bf(ox); o4.y = f2bf(oy); o4.z = f2bf(oz); o4.w = f2bf(ow);
        *(ushort4*)(outb + (size_t)row * C + tid * 4) = o4;
    } else {
        *(float4*)(outf + (size_t)row * C + tid * 4) = make_float4(ox, oy, oz, ow);
    }
}

extern "C" void kernel_launch(void* const* d_in, const int* in_sizes, int n_in,
                              void* d_out, int out_size, void* d_ws, size_t ws_size,
                              hipStream_t stream)
{
    const float* x    = (const float*)d_in[0];
    const float* Wq   = (const float*)d_in[1];
    const float* bq   = (const float*)d_in[2];
    const float* Wk   = (const float*)d_in[3];
    const float* bk   = (const float*)d_in[4];
    const float* Wv   = (const float*)d_in[5];
    const float* bv   = (const float*)d_in[6];
    const float* W1   = (const float*)d_in[7];
    const float* b1   = (const float*)d_in[8];
    const float* W2   = (const float*)d_in[9];
    const float* b2   = (const float*)d_in[10];
    const float* ln_w = (const float*)d_in[11];
    float* out = (float*)d_out;
    char* ws = (char*)d_ws;

    const int B = 2, T = 2048, C = 1024, DFF = 4096;
    const int M = B * T;                 // 4096
    const size_t MB = 1048576;

    unsigned short* qk_bf = (unsigned short*)(ws);             // 16 MB [4096][2048]
    unsigned short* vt_bf = (unsigned short*)(ws + 16 * MB);   //  8 MB [1024][4096]
    float*          a     = (float*)(ws + 24 * MB);            // 16 MB [4096][1024]
    unsigned short* x_bf  = (unsigned short*)(ws + 40 * MB);   //  8 MB [4096][1024]
    unsigned short* Wqk_t = (unsigned short*)(ws + 48 * MB);   //  4 MB [2048][1024]
    unsigned short* Wvt   = (unsigned short*)(ws + 52 * MB);   //  2 MB [1024][1024]
    unsigned short* W1t   = (unsigned short*)(ws + 54 * MB);   //  8 MB [4096][1024]
    unsigned short* W2t   = (unsigned short*)(ws + 62 * MB);   //  8 MB [1024][4096]
    float*          bqk   = (float*)(ws + 70 * MB);            //  8 KB [2048]
    unsigned short* u_bf  = (unsigned short*)(ws + 71 * MB);   // 32 MB [4096][4096]
    unsigned short* h_bf  = x_bf;                              // reuse (x dead)
    float*          f     = (float*)(ws);                      // 16 MB, reuse qk

    dim3 blk(256);

    // One merged preprocessing dispatch.
    prep_kernel<<<dim3(15368), blk, 0, stream>>>(
        x, Wq, Wk, Wv, W1, W2, bq, bk,
        x_bf, Wqk_t, Wvt, W1t, W2t, bqk);

    // QK projection + V^T in one dual dispatch, both <64,64,2> (tri 48 KB).
    gemm_dual<64, 64, 2><<<dim3(3072), blk, 0, stream>>>(
        x_bf, Wqk_t, bqk, qk_bf, M, 2 * C, C, 2, 2048, 32,
        Wvt, x_bf, bv, vt_bf, C, M, C, 3, 64);

    fattn_mfma<<<dim3(1024), blk, 0, stream>>>(qk_bf, vt_bf, a);

    add_ln_kernel<<<dim3(M), blk, 0, stream>>>(a, ln_w, nullptr, h_bf, 1);

    // FFN1: [4096,1024] x [1024,4096] -> relu -> bf16. <64,128,2> tri 72 KB.
    gemm_bf16_mfma<64, 128, 2><<<dim3(DFF / 128, M / 64), blk, 0, stream>>>(
        h_bf, W1t, b1, nullptr, u_bf, M, DFF, C, 1);

    // FFN2: [4096,4096] x [4096,1024] -> fp32. <128,64,2> tri 72 KB,
    // flat 512 blocks with XCD swizzle (grid 16 cols x 32 rows; 4 rows/XCD).
    gemm_xcd<128, 64, 2><<<dim3(512), blk, 0, stream>>>(
        u_bf, W2t, b2, f, nullptr, M, C, DFF, 0, 16, 4);

    add_ln_kernel<<<dim3(M), blk, 0, stream>>>(f, ln_w, out, nullptr, 0);
}

// Round 5
// 345.329 us; speedup vs baseline: 1.0405x; 1.0405x over previous
//
#include <hip/hip_runtime.h>
#include <math.h>

// ---------------------------------------------------------------------------
// Decoder block: x -> QKV proj -> causal MHA -> a + LN(a) -> FFN -> f + LN(f)
// B=2 T=2048 C=1024 NH=16 hd=64 DFF=4096, fp32 in/out.
// Round 19:
//   * R18 (tri-buffer counted vmcnt) regressed: 72 KB LDS -> 2 blocks/CU
//     (m132 failure mode). Reverted to the 1-phase 2-barrier loop.
//   * Unifying model across R14-R18: staging BW is pinned ~13.4 TB/s; perf
//     = 13.4 TB/s x (FLOP/staged-byte). <64,128> = 43.7 F/B -> 586 TF
//     (measured 577); m97's <128,128,BK=32> = 65.5 F/B -> 878 (874).
//   * So: every GEMM moves to the m97-exact tile <128,128,NP=1>: BK=32,
//     16 KB LDS, 4 waves, per-wave 64x64 (4x4 frags, 64 acc VGPRs).
//   * FFN2 at <128,128> would be 256 blocks = 1/CU -> split-K=2 (R16-proven
//     gemm_splitk + add_ln in2 sum), 512 blocks = 2/CU.
//   * fattn/prep unchanged.
// ---------------------------------------------------------------------------

typedef __attribute__((ext_vector_type(8))) short short8;
typedef __attribute__((ext_vector_type(4))) float f32x4;

__device__ __forceinline__ unsigned short f2bf(float f) {
    unsigned u = __builtin_bit_cast(unsigned, f);
    unsigned r = u + 0x7fffu + ((u >> 16) & 1u);   // RNE
    return (unsigned short)(r >> 16);
}

// ---------------------------------------------------------------------------
// Merged preprocessing. Grid = 15368 blocks of 256.
// ---------------------------------------------------------------------------
__global__ __launch_bounds__(256) void prep_kernel(
    const float* __restrict__ x,  const float* __restrict__ Wq,
    const float* __restrict__ Wk, const float* __restrict__ Wv,
    const float* __restrict__ W1, const float* __restrict__ W2,
    const float* __restrict__ bq, const float* __restrict__ bk,
    unsigned short* __restrict__ x_bf,  unsigned short* __restrict__ Wqk_t,
    unsigned short* __restrict__ Wvt,   unsigned short* __restrict__ W1t,
    unsigned short* __restrict__ W2t,   float* __restrict__ bqk)
{
    const int bid = blockIdx.x;
    const int tid = threadIdx.x;

    if (bid < 4096) {                       // x convert
        const int i = (bid * 256 + tid) * 4;
        float4 v = *(const float4*)(x + i);
        ushort4 o;
        o.x = f2bf(v.x); o.y = f2bf(v.y); o.z = f2bf(v.z); o.w = f2bf(v.w);
        *(ushort4*)(x_bf + i) = o;
        return;
    }
    if (bid >= 15360) {                     // bias concat
        const int i = (bid - 15360) * 256 + tid;
        bqk[i] = i < 1024 ? bq[i] : bk[i - 1024];
        return;
    }

    __shared__ float tile[32][33];
    const float* src; unsigned short* dst; int K, N, t;
    if (bid < 5120)       { t = bid - 4096;  src = Wq; dst = Wqk_t;            K = 1024; N = 1024; }
    else if (bid < 6144)  { t = bid - 5120;  src = Wk; dst = Wqk_t + 1048576;  K = 1024; N = 1024; }
    else if (bid < 7168)  { t = bid - 6144;  src = Wv; dst = Wvt;              K = 1024; N = 1024; }
    else if (bid < 11264) { t = bid - 7168;  src = W1; dst = W1t;              K = 1024; N = 4096; }
    else                  { t = bid - 11264; src = W2; dst = W2t;              K = 4096; N = 1024; }

    const int ncols = N >> 5;
    const int n0 = (t % ncols) * 32;
    const int k0 = (t / ncols) * 32;
    const int tx = tid & 31;
    const int ty = tid >> 5;                // 0..7
#pragma unroll
    for (int i = 0; i < 4; ++i)
        tile[ty + i * 8][tx] = src[(size_t)(k0 + ty + i * 8) * N + n0 + tx];
    __syncthreads();
#pragma unroll
    for (int i = 0; i < 4; ++i)
        dst[(size_t)(n0 + ty + i * 8) * K + k0 + tx] = f2bf(tile[tx][ty + i * 8]);
}

// ---------------------------------------------------------------------------
// GEMM body: C[M][N] = A[M][K] . Bt[N][K]^T + bias over K range [kbeg,kend).
// TMxTN tile at (bx, by), NP 32-wide LDS planes per barrier pair.
// mode: 0 = fp32 out, bias[col]; 1 = relu->bf16, bias[col];
//       2 = bf16, bias[col];     3 = bf16, bias[row]; 4 = fp32, no bias.
// ---------------------------------------------------------------------------
template <int TM, int TN, int NP>
__device__ __forceinline__ void gemm_body(
    unsigned short* AsB, unsigned short* BsB,
    const unsigned short* __restrict__ A, const unsigned short* __restrict__ Bt,
    const float* __restrict__ bias, float* __restrict__ Cf,
    unsigned short* __restrict__ Cb, int M, int N, int K, int mode,
    int bx, int by, int kbeg, int kend)
{
    constexpr int NI   = TM / 32;
    constexpr int NJ   = TN / 32;
    constexpr int NCA  = TM / 16;
    constexpr int NCB  = TN / 16;
    constexpr int MAXA = (NCA + 3) / 4;
    constexpr int MAXB = (NCB + 3) / 4;

    const int tid  = threadIdx.x;
    const int lane = tid & 63;
    const int w    = tid >> 6;
    const int wm   = (w & 1) * (TM / 2);
    const int wn   = (w >> 1) * (TN / 2);
    const int fm   = lane & 15;
    const int quad = lane >> 4;

    const int row0 = by * TM;
    const int col0 = bx * TN;

    const int srow = lane >> 2;
    const int scol = (lane & 3) * 8;

    const unsigned short* aptr[MAXA];
    int aoff[MAXA];
#pragma unroll
    for (int i = 0; i < MAXA; ++i) {
        const int c = w + i * 4;
        if (c < NCA) {
            aptr[i] = A + (size_t)(row0 + c * 16 + srow) * K + scol;
            aoff[i] = c * 16 * 32;
        }
    }
    const unsigned short* bptr[MAXB];
    int boff[MAXB];
#pragma unroll
    for (int i = 0; i < MAXB; ++i) {
        const int c = w + i * 4;
        if (c < NCB) {
            bptr[i] = Bt + (size_t)(col0 + c * 16 + srow) * K + scol;
            boff[i] = c * 16 * 32;
        }
    }

    f32x4 acc[NI][NJ] = {};

    for (int k0 = kbeg; k0 < kend; k0 += NP * 32) {
        __syncthreads();
#pragma unroll
        for (int p = 0; p < NP; ++p) {
#pragma unroll
            for (int i = 0; i < MAXA; ++i)
                if (w + i * 4 < NCA)          // wave-uniform
                    __builtin_amdgcn_global_load_lds(
                        (const __attribute__((address_space(1))) void*)(aptr[i] + k0 + p * 32),
                        (__attribute__((address_space(3))) void*)&AsB[p * TM * 32 + aoff[i]], 16, 0, 0);
#pragma unroll
            for (int i = 0; i < MAXB; ++i)
                if (w + i * 4 < NCB)          // wave-uniform
                    __builtin_amdgcn_global_load_lds(
                        (const __attribute__((address_space(1))) void*)(bptr[i] + k0 + p * 32),
                        (__attribute__((address_space(3))) void*)&BsB[p * TN * 32 + boff[i]], 16, 0, 0);
        }
        __syncthreads();

#pragma unroll
        for (int p = 0; p < NP; ++p) {
            short8 af[NI], bf[NJ];
#pragma unroll
            for (int i = 0; i < NI; ++i)
                af[i] = *(const short8*)&AsB[p * TM * 32 + (wm + i * 16 + fm) * 32 + quad * 8];
#pragma unroll
            for (int j = 0; j < NJ; ++j)
                bf[j] = *(const short8*)&BsB[p * TN * 32 + (wn + j * 16 + fm) * 32 + quad * 8];
#pragma unroll
            for (int i = 0; i < NI; ++i)
#pragma unroll
                for (int j = 0; j < NJ; ++j)
                    acc[i][j] = __builtin_amdgcn_mfma_f32_16x16x32_bf16(
                        af[i], bf[j], acc[i][j], 0, 0, 0);
        }
    }

    // Epilogue. C/D layout: col = lane&15, row = quad*4 + reg.
#pragma unroll
    for (int j = 0; j < NJ; ++j) {
        const int col = col0 + wn + j * 16 + fm;
        const float bcol = (mode == 3 || mode == 4) ? 0.f : bias[col];
#pragma unroll
        for (int i = 0; i < NI; ++i) {
            const int rbase = row0 + wm + i * 16 + quad * 4;
#pragma unroll
            for (int r = 0; r < 4; ++r) {
                const int row = rbase + r;
                float val = acc[i][j][r] + ((mode == 3) ? bias[row] : bcol);
                if (mode == 1) val = fmaxf(val, 0.f);
                if (mode == 0 || mode == 4) Cf[(size_t)row * N + col] = val;
                else                        Cb[(size_t)row * N + col] = f2bf(val);
            }
        }
    }
}

template <int TM, int TN, int NP>
__global__ __launch_bounds__(256) void gemm_bf16_mfma(
    const unsigned short* __restrict__ A, const unsigned short* __restrict__ Bt,
    const float* __restrict__ bias, float* __restrict__ Cf,
    unsigned short* __restrict__ Cb, int M, int N, int K, int mode)
{
    __shared__ unsigned short As[NP * TM * 32];
    __shared__ unsigned short Bs[NP * TN * 32];
    gemm_body<TM, TN, NP>(As, Bs, A, Bt, bias, Cf, Cb, M, N, K, mode,
                          blockIdx.x, blockIdx.y, 0, K);
}

// Split-K=2 GEMM: blocks [0,nbh) compute K/2 low half -> C0 (mode 0, bias);
// blocks [nbh,2*nbh) compute high half -> C1 (mode 4, no bias). Per half:
// grid nxh cols x (8*rows_per_xcd_h) rows, row-stripe per XCD (bid&7).
template <int TM, int TN, int NP>
__global__ __launch_bounds__(256) void gemm_splitk(
    const unsigned short* __restrict__ A, const unsigned short* __restrict__ Bt,
    const float* __restrict__ bias, float* __restrict__ C0,
    float* __restrict__ C1, int M, int N, int K,
    int nxh, int rows_per_xcd_h, int nbh)
{
    __shared__ unsigned short As[NP * TM * 32];
    __shared__ unsigned short Bs[NP * TN * 32];
    const int half = blockIdx.x >= nbh;
    const int r    = blockIdx.x - (half ? nbh : 0);
    const int xcd  = blockIdx.x & 7;
    const int idx  = r >> 3;
    const int bx   = idx % nxh;
    const int by   = xcd * rows_per_xcd_h + idx / nxh;
    const int kb   = half ? (K >> 1) : 0;
    gemm_body<TM, TN, NP>(As, Bs, A, Bt, bias, half ? C1 : C0, nullptr,
                          M, N, K, half ? 4 : 0, bx, by, kb, kb + (K >> 1));
}

// Two independent GEMMs (same tile config) in one flat-grid dispatch.
template <int TM, int TN, int NP>
__global__ __launch_bounds__(256) void gemm_dual(
    const unsigned short* __restrict__ A0, const unsigned short* __restrict__ B0,
    const float* __restrict__ bias0, unsigned short* __restrict__ C0,
    int M0, int N0, int K0, int mode0, int nb0, int nx0,
    const unsigned short* __restrict__ A1, const unsigned short* __restrict__ B1,
    const float* __restrict__ bias1, unsigned short* __restrict__ C1,
    int M1, int N1, int K1, int mode1, int nx1)
{
    __shared__ unsigned short As[NP * TM * 32];
    __shared__ unsigned short Bs[NP * TN * 32];
    const int bid = blockIdx.x;
    if (bid < nb0) {
        gemm_body<TM, TN, NP>(As, Bs, A0, B0, bias0, nullptr, C0,
                              M0, N0, K0, mode0, bid % nx0, bid / nx0, 0, K0);
    } else {
        const int t = bid - nb0;
        gemm_body<TM, TN, NP>(As, Bs, A1, B1, bias1, nullptr, C1,
                              M1, N1, K1, mode1, t % nx1, t / nx1, 0, K1);
    }
}

// ---------------------------------------------------------------------------
// MFMA flash attention v2. qk: [4096][2048] bf16 (q cols 0..1023, k 1024..),
// vt: [1024][4096] bf16 (row = h*64+d, col = b*2048+t), a: [4096][1024] fp32.
// ---------------------------------------------------------------------------
__global__ __launch_bounds__(256) void fattn_mfma(
    const unsigned short* __restrict__ qk,
    const unsigned short* __restrict__ vt,
    float* __restrict__ a)
{
    const int T = 2048, LDQK = 2048, LDVT = 4096, OUTC = 1024;
    const float cs = 0.04508422f;       // (1/32) * log2(e)

    __shared__ unsigned short Qs[2][64][32];
    __shared__ unsigned short Ks[2][64][32];
    __shared__ unsigned short Vs[2][64][32];
    __shared__ unsigned short Ps[4][16][72];

    const int tid  = threadIdx.x;
    const int lane = tid & 63;
    const int w    = tid >> 6;
    const int fm   = lane & 15;
    const int quad = lane >> 4;
    const int srow = lane >> 2;
    const int scol = (lane & 3) * 8;

    const int n  = blockIdx.x;
    const int lo = n & 255, hi = n >> 8;
    const int h  = ((lo >> 5) & 7) | ((hi & 1) << 3);
    const int b  = hi >> 1;
    const int qv = lo & 31;
    const int u  = ((qv & 1) << 4) | ((qv & 2) << 2) | (qv & 4) |
                   ((qv & 8) >> 2) | ((qv & 16) >> 4);
    const int qb = (hi & 1) ? (31 - u) : u;
    const int q0 = qb * 64;

    const size_t rowbase = (size_t)b * T;

#pragma unroll
    for (int i = 0; i < 2; ++i) {
        const int c  = w * 2 + i;
        const int kh = c & 1, rg = c >> 1;
        const unsigned short* src = qk + (rowbase + q0 + rg * 16 + srow) * LDQK
                                       + h * 64 + kh * 32 + scol;
        __builtin_amdgcn_global_load_lds(
            (const __attribute__((address_space(1))) void*)src,
            (__attribute__((address_space(3))) void*)&Qs[kh][rg * 16][0], 16, 0, 0);
    }
    __syncthreads();
    short8 qf0 = *(const short8*)&Qs[0][w * 16 + fm][quad * 8];
    short8 qf1 = *(const short8*)&Qs[1][w * 16 + fm][quad * 8];

    short8 ones;
#pragma unroll
    for (int i = 0; i < 8; ++i) ones[i] = (short)0x3F80;   // bf16 1.0

    f32x4 o[4] = {};
    f32x4 lacc = {};

    const int qglob = q0 + w * 16 + fm;

    for (int jt = 0; jt <= qb; ++jt) {
        const int j0 = jt * 64;
        __syncthreads();
#pragma unroll
        for (int i = 0; i < 2; ++i) {
            const int c  = w * 2 + i;
            const int kh = c & 1, rg = c >> 1;
            const unsigned short* ksrc = qk + (rowbase + j0 + rg * 16 + srow) * LDQK
                                            + 1024 + h * 64 + kh * 32 + scol;
            __builtin_amdgcn_global_load_lds(
                (const __attribute__((address_space(1))) void*)ksrc,
                (__attribute__((address_space(3))) void*)&Ks[kh][rg * 16][0], 16, 0, 0);
            const unsigned short* vsrc = vt + (size_t)(h * 64 + rg * 16 + srow) * LDVT
                                            + rowbase + j0 + kh * 32 + scol;
            __builtin_amdgcn_global_load_lds(
                (const __attribute__((address_space(1))) void*)vsrc,
                (__attribute__((address_space(3))) void*)&Vs[kh][rg * 16][0], 16, 0, 0);
        }
        __syncthreads();

        // S^T = K . Q^T
        f32x4 s[4];
#pragma unroll
        for (int j = 0; j < 4; ++j) {
            short8 k0 = *(const short8*)&Ks[0][j * 16 + fm][quad * 8];
            short8 k1 = *(const short8*)&Ks[1][j * 16 + fm][quad * 8];
            f32x4 acc = {};
            acc = __builtin_amdgcn_mfma_f32_16x16x32_bf16(k0, qf0, acc, 0, 0, 0);
            acc = __builtin_amdgcn_mfma_f32_16x16x32_bf16(k1, qf1, acc, 0, 0, 0);
            s[j] = acc;
        }

        if (jt == qb) {
#pragma unroll
            for (int j = 0; j < 4; ++j) {
                const int kbase = j0 + j * 16 + quad * 4;
#pragma unroll
                for (int r = 0; r < 4; ++r) {
                    const float e = exp2f(s[j][r] * cs);
                    s[j][r] = (kbase + r > qglob) ? 0.f : e;
                }
            }
        } else {
#pragma unroll
            for (int j = 0; j < 4; ++j)
#pragma unroll
                for (int r = 0; r < 4; ++r)
                    s[j][r] = exp2f(s[j][r] * cs);
        }

#pragma unroll
        for (int j = 0; j < 4; ++j) {
            const unsigned d0 = (unsigned)f2bf(s[j][0]) | ((unsigned)f2bf(s[j][1]) << 16);
            const unsigned d1 = (unsigned)f2bf(s[j][2]) | ((unsigned)f2bf(s[j][3]) << 16);
            *(uint2*)&Ps[w][fm][j * 16 + quad * 4] = make_uint2(d0, d1);
        }
        short8 pf0 = *(const short8*)&Ps[w][fm][quad * 8];
        short8 pf1 = *(const short8*)&Ps[w][fm][32 + quad * 8];

#pragma unroll
        for (int jd = 0; jd < 4; ++jd) {
            short8 v0 = *(const short8*)&Vs[0][jd * 16 + fm][quad * 8];
            short8 v1 = *(const short8*)&Vs[1][jd * 16 + fm][quad * 8];
            o[jd] = __builtin_amdgcn_mfma_f32_16x16x32_bf16(pf0, v0, o[jd], 0, 0, 0);
            o[jd] = __builtin_amdgcn_mfma_f32_16x16x32_bf16(pf1, v1, o[jd], 0, 0, 0);
        }
        lacc = __builtin_amdgcn_mfma_f32_16x16x32_bf16(pf0, ones, lacc, 0, 0, 0);
        lacc = __builtin_amdgcn_mfma_f32_16x16x32_bf16(pf1, ones, lacc, 0, 0, 0);
    }

    const size_t orow = rowbase + q0 + w * 16 + quad * 4;
#pragma unroll
    for (int r = 0; r < 4; ++r) {
        const float inv = 1.0f / lacc[r];
#pragma unroll
        for (int jd = 0; jd < 4; ++jd)
            a[(orow + r) * OUTC + h * 64 + jd * 16 + fm] = o[jd][r] * inv;
    }
}

// out = in (+ in2) + LayerNorm(in (+ in2))*w.
// bf16_out=1 -> write bf16 to outb, else fp32 outf.
__global__ __launch_bounds__(256) void add_ln_kernel(
    const float* __restrict__ in, const float* __restrict__ in2,
    const float* __restrict__ w,
    float* __restrict__ outf, unsigned short* __restrict__ outb, int bf16_out)
{
    const int C = 1024;
    const int row = blockIdx.x;
    const int tid = threadIdx.x;

    __shared__ float red[256];

    const float* x = in + (size_t)row * C;
    float4 xv = *(const float4*)(x + tid * 4);
    if (in2) {
        float4 yv = *(const float4*)(in2 + (size_t)row * C + tid * 4);
        xv.x += yv.x; xv.y += yv.y; xv.z += yv.z; xv.w += yv.w;
    }

    red[tid] = xv.x + xv.y + xv.z + xv.w;
    __syncthreads();
    for (int off = 128; off > 0; off >>= 1) {
        if (tid < off) red[tid] += red[tid + off];
        __syncthreads();
    }
    const float mu = red[0] * (1.0f / 1024.0f);
    __syncthreads();

    float dx = xv.x - mu, dy = xv.y - mu, dz = xv.z - mu, dw = xv.w - mu;
    red[tid] = dx * dx + dy * dy + dz * dz + dw * dw;
    __syncthreads();
    for (int off = 128; off > 0; off >>= 1) {
        if (tid < off) red[tid] += red[tid + off];
        __syncthreads();
    }
    const float rstd = rsqrtf(red[0] * (1.0f / 1024.0f) + 1e-5f);

    float4 wv = *(const float4*)(w + tid * 4);
    float ox = xv.x + dx * rstd * wv.x;
    float oy = xv.y + dy * rstd * wv.y;
    float oz = xv.z + dz * rstd * wv.z;
    float ow = xv.w + dw * rstd * wv.w;
    if (bf16_out) {
        ushort4 o4;
        o4.x = f2bf(ox); o4.y = f2bf(oy); o4.z = f2bf(oz); o4.w = f2bf(ow);
        *(ushort4*)(outb + (size_t)row * C + tid * 4) = o4;
    } else {
        *(float4*)(outf + (size_t)row * C + tid * 4) = make_float4(ox, oy, oz, ow);
    }
}

extern "C" void kernel_launch(void* const* d_in, const int* in_sizes, int n_in,
                              void* d_out, int out_size, void* d_ws, size_t ws_size,
                              hipStream_t stream)
{
    const float* x    = (const float*)d_in[0];
    const float* Wq   = (const float*)d_in[1];
    const float* bq   = (const float*)d_in[2];
    const float* Wk   = (const float*)d_in[3];
    const float* bk   = (const float*)d_in[4];
    const float* Wv   = (const float*)d_in[5];
    const float* bv   = (const float*)d_in[6];
    const float* W1   = (const float*)d_in[7];
    const float* b1   = (const float*)d_in[8];
    const float* W2   = (const float*)d_in[9];
    const float* b2   = (const float*)d_in[10];
    const float* ln_w = (const float*)d_in[11];
    float* out = (float*)d_out;
    char* ws = (char*)d_ws;

    const int B = 2, T = 2048, C = 1024, DFF = 4096;
    const int M = B * T;                 // 4096
    const size_t MB = 1048576;

    unsigned short* qk_bf = (unsigned short*)(ws);             // 16 MB [4096][2048]
    unsigned short* vt_bf = (unsigned short*)(ws + 16 * MB);   //  8 MB [1024][4096]
    float*          a     = (float*)(ws + 24 * MB);            // 16 MB [4096][1024]
    unsigned short* x_bf  = (unsigned short*)(ws + 40 * MB);   //  8 MB [4096][1024]
    unsigned short* Wqk_t = (unsigned short*)(ws + 48 * MB);   //  4 MB [2048][1024]
    unsigned short* Wvt   = (unsigned short*)(ws + 52 * MB);   //  2 MB [1024][1024]
    unsigned short* W1t   = (unsigned short*)(ws + 54 * MB);   //  8 MB [4096][1024]
    unsigned short* W2t   = (unsigned short*)(ws + 62 * MB);   //  8 MB [1024][4096]
    float*          bqk   = (float*)(ws + 70 * MB);            //  8 KB [2048]
    unsigned short* u_bf  = (unsigned short*)(ws + 71 * MB);   // 32 MB [4096][4096]
    unsigned short* h_bf  = x_bf;                              // reuse (x dead)
    float*          f     = (float*)(ws);                      // 16 MB, reuse qk (dead)
    float*          f2    = a;                                 // 16 MB, reuse a  (dead)

    dim3 blk(256);

    // One merged preprocessing dispatch.
    prep_kernel<<<dim3(15368), blk, 0, stream>>>(
        x, Wq, Wk, Wv, W1, W2, bq, bk,
        x_bf, Wqk_t, Wvt, W1t, W2t, bqk);

    // QK projection + V^T in one dual dispatch, both <128,128,1> (16 KB LDS).
    // QK: [4096,2048] grid 16x32 = 512; V^T: [1024,4096] grid 32x8 = 256.
    gemm_dual<128, 128, 1><<<dim3(768), blk, 0, stream>>>(
        x_bf, Wqk_t, bqk, qk_bf, M, 2 * C, C, 2, 512, 16,
        Wvt, x_bf, bv, vt_bf, C, M, C, 3, 32);

    fattn_mfma<<<dim3(1024), blk, 0, stream>>>(qk_bf, vt_bf, a);

    add_ln_kernel<<<dim3(M), blk, 0, stream>>>(a, nullptr, ln_w, nullptr, h_bf, 1);

    // FFN1: [4096,1024] x [1024,4096] -> relu -> bf16. <128,128,1>,
    // grid 32x32 plain.
    gemm_bf16_mfma<128, 128, 1><<<dim3(DFF / 128, M / 128), blk, 0, stream>>>(
        h_bf, W1t, b1, nullptr, u_bf, M, DFF, C, 1);

    // FFN2: [4096,4096] x [4096,1024] -> fp32, split-K=2. <128,128,1>,
    // 512 blocks (256/half, per-half grid 8x32, 4 row-tiles per XCD).
    gemm_splitk<128, 128, 1><<<dim3(512), blk, 0, stream>>>(
        u_bf, W2t, b2, f, f2, M, C, DFF, 8, 4, 256);

    add_ln_kernel<<<dim3(M), blk, 0, stream>>>(f, f2, ln_w, out, nullptr, 0);
}

// Round 6
// 318.831 us; speedup vs baseline: 1.1269x; 1.0831x over previous
//
#include <hip/hip_runtime.h>
#include <math.h>

// ---------------------------------------------------------------------------
// Decoder block: x -> QKV proj -> causal MHA -> a + LN(a) -> FFN -> f + LN(f)
// B=2 T=2048 C=1024 NH=16 hd=64 DFF=4096, fp32 in/out.
// Round 20:
//   * Diagnosis: every staging load read 64 B per A/B row (16-row x 32-col
//     subtiles) = 50% of a 128 B line -> the "13.4 TB/s staging ceiling" of
//     R14-R19 is ~27 TB/s of L2 line traffic at half sector efficiency.
//     All tile/pipeline reshuffles were null because none changed
//     bytes-per-line. Also the old LDS layout's A-frag ds_read_b128 was
//     8-way bank-conflicted.
//   * Fix, structure-preserving (1-phase 2-barrier loop kept): BK=64,
//     staging in 8-row panels with 128 B contiguous per row (full lines).
//     Both-sides XOR swizzle (rule #21): LDS linear for global_load_lds,
//     SOURCE col-slot = (lane&7)^(lane>>3), ds_read slot = col16^(row&7).
//     Fragment reads now 2 lanes/slot = conflict-free.
//   * Tiles at R14-proven shapes: dual <64,64>, FFN1 <64,128>,
//     FFN2 <128,64> + XCD swizzle. 32 MFMA per barrier pair.
// ---------------------------------------------------------------------------

typedef __attribute__((ext_vector_type(8))) short short8;
typedef __attribute__((ext_vector_type(4))) float f32x4;

__device__ __forceinline__ unsigned short f2bf(float f) {
    unsigned u = __builtin_bit_cast(unsigned, f);
    unsigned r = u + 0x7fffu + ((u >> 16) & 1u);   // RNE
    return (unsigned short)(r >> 16);
}

// ---------------------------------------------------------------------------
// Merged preprocessing. Grid = 15368 blocks of 256.
// ---------------------------------------------------------------------------
__global__ __launch_bounds__(256) void prep_kernel(
    const float* __restrict__ x,  const float* __restrict__ Wq,
    const float* __restrict__ Wk, const float* __restrict__ Wv,
    const float* __restrict__ W1, const float* __restrict__ W2,
    const float* __restrict__ bq, const float* __restrict__ bk,
    unsigned short* __restrict__ x_bf,  unsigned short* __restrict__ Wqk_t,
    unsigned short* __restrict__ Wvt,   unsigned short* __restrict__ W1t,
    unsigned short* __restrict__ W2t,   float* __restrict__ bqk)
{
    const int bid = blockIdx.x;
    const int tid = threadIdx.x;

    if (bid < 4096) {                       // x convert
        const int i = (bid * 256 + tid) * 4;
        float4 v = *(const float4*)(x + i);
        ushort4 o;
        o.x = f2bf(v.x); o.y = f2bf(v.y); o.z = f2bf(v.z); o.w = f2bf(v.w);
        *(ushort4*)(x_bf + i) = o;
        return;
    }
    if (bid >= 15360) {                     // bias concat
        const int i = (bid - 15360) * 256 + tid;
        bqk[i] = i < 1024 ? bq[i] : bk[i - 1024];
        return;
    }

    __shared__ float tile[32][33];
    const float* src; unsigned short* dst; int K, N, t;
    if (bid < 5120)       { t = bid - 4096;  src = Wq; dst = Wqk_t;            K = 1024; N = 1024; }
    else if (bid < 6144)  { t = bid - 5120;  src = Wk; dst = Wqk_t + 1048576;  K = 1024; N = 1024; }
    else if (bid < 7168)  { t = bid - 6144;  src = Wv; dst = Wvt;              K = 1024; N = 1024; }
    else if (bid < 11264) { t = bid - 7168;  src = W1; dst = W1t;              K = 1024; N = 4096; }
    else                  { t = bid - 11264; src = W2; dst = W2t;              K = 4096; N = 1024; }

    const int ncols = N >> 5;
    const int n0 = (t % ncols) * 32;
    const int k0 = (t / ncols) * 32;
    const int tx = tid & 31;
    const int ty = tid >> 5;                // 0..7
#pragma unroll
    for (int i = 0; i < 4; ++i)
        tile[ty + i * 8][tx] = src[(size_t)(k0 + ty + i * 8) * N + n0 + tx];
    __syncthreads();
#pragma unroll
    for (int i = 0; i < 4; ++i)
        dst[(size_t)(n0 + ty + i * 8) * K + k0 + tx] = f2bf(tile[tx][ty + i * 8]);
}

// ---------------------------------------------------------------------------
// GEMM body: C[M][N] = A[M][K] . Bt[N][K]^T + bias. 1-phase 2-barrier loop,
// BK=64. LDS: [rows][64] shorts, staged in 8-row panels, 128 B/row (full
// cache lines). Both-sides XOR swizzle: source col-slot (lane&7)^(lane>>3),
// read slot col16 ^ (row&7).
// mode: 0 = fp32 out, bias[col]; 1 = relu->bf16, bias[col];
//       2 = bf16, bias[col];     3 = bf16, bias[row].
// ---------------------------------------------------------------------------
template <int TM, int TN>
__device__ __forceinline__ void gemm_body(
    unsigned short* As, unsigned short* Bs,
    const unsigned short* __restrict__ A, const unsigned short* __restrict__ Bt,
    const float* __restrict__ bias, float* __restrict__ Cf,
    unsigned short* __restrict__ Cb, int M, int N, int K, int mode,
    int bx, int by)
{
    constexpr int NI   = TM / 32;
    constexpr int NJ   = TN / 32;
    constexpr int NPA  = TM / 8;            // 8-row panels
    constexpr int NPB  = TN / 8;
    constexpr int MAXA = (NPA + 3) / 4;
    constexpr int MAXB = (NPB + 3) / 4;

    const int tid  = threadIdx.x;
    const int lane = tid & 63;
    const int w    = tid >> 6;
    const int wm   = (w & 1) * (TM / 2);
    const int wn   = (w >> 1) * (TN / 2);
    const int fm   = lane & 15;
    const int quad = lane >> 4;

    const int row0 = by * TM;
    const int col0 = bx * TN;

    // Staging lane geometry: 8 rows x 128 B contiguous, source pre-swizzled.
    const int srow = lane >> 3;                  // 0..7
    const int scol = ((lane & 7) ^ srow) << 3;   // swizzled col (shorts)

    const unsigned short* aptr[MAXA];
    int aoff[MAXA];
#pragma unroll
    for (int i = 0; i < MAXA; ++i) {
        const int p = w + i * 4;
        if (p < NPA) {
            aptr[i] = A + (size_t)(row0 + p * 8 + srow) * K + scol;
            aoff[i] = p * 8 * 64;                // shorts
        }
    }
    const unsigned short* bptr[MAXB];
    int boff[MAXB];
#pragma unroll
    for (int i = 0; i < MAXB; ++i) {
        const int p = w + i * 4;
        if (p < NPB) {
            bptr[i] = Bt + (size_t)(col0 + p * 8 + srow) * K + scol;
            boff[i] = p * 8 * 64;
        }
    }

    f32x4 acc[NI][NJ] = {};

    for (int k0 = 0; k0 < K; k0 += 64) {
        __syncthreads();
#pragma unroll
        for (int i = 0; i < MAXA; ++i)
            if (w + i * 4 < NPA)          // wave-uniform
                __builtin_amdgcn_global_load_lds(
                    (const __attribute__((address_space(1))) void*)(aptr[i] + k0),
                    (__attribute__((address_space(3))) void*)&As[aoff[i]], 16, 0, 0);
#pragma unroll
        for (int i = 0; i < MAXB; ++i)
            if (w + i * 4 < NPB)          // wave-uniform
                __builtin_amdgcn_global_load_lds(
                    (const __attribute__((address_space(1))) void*)(bptr[i] + k0),
                    (__attribute__((address_space(3))) void*)&Bs[boff[i]], 16, 0, 0);
        __syncthreads();

#pragma unroll
        for (int kh = 0; kh < 2; ++kh) {
            short8 af[NI], bf[NJ];
#pragma unroll
            for (int i = 0; i < NI; ++i) {
                const int r = wm + i * 16 + fm;
                const int sl = ((kh << 2) | quad) ^ (r & 7);
                af[i] = *(const short8*)&As[r * 64 + sl * 8];
            }
#pragma unroll
            for (int j = 0; j < NJ; ++j) {
                const int r = wn + j * 16 + fm;
                const int sl = ((kh << 2) | quad) ^ (r & 7);
                bf[j] = *(const short8*)&Bs[r * 64 + sl * 8];
            }
#pragma unroll
            for (int i = 0; i < NI; ++i)
#pragma unroll
                for (int j = 0; j < NJ; ++j)
                    acc[i][j] = __builtin_amdgcn_mfma_f32_16x16x32_bf16(
                        af[i], bf[j], acc[i][j], 0, 0, 0);
        }
    }

    // Epilogue. C/D layout: col = lane&15, row = quad*4 + reg.
#pragma unroll
    for (int j = 0; j < NJ; ++j) {
        const int col = col0 + wn + j * 16 + fm;
        const float bcol = (mode == 3) ? 0.f : bias[col];
#pragma unroll
        for (int i = 0; i < NI; ++i) {
            const int rbase = row0 + wm + i * 16 + quad * 4;
#pragma unroll
            for (int r = 0; r < 4; ++r) {
                const int row = rbase + r;
                float val = acc[i][j][r] + ((mode == 3) ? bias[row] : bcol);
                if (mode == 1) val = fmaxf(val, 0.f);
                if (mode == 0) Cf[(size_t)row * N + col] = val;
                else           Cb[(size_t)row * N + col] = f2bf(val);
            }
        }
    }
}

template <int TM, int TN>
__global__ __launch_bounds__(256) void gemm_bf16_mfma(
    const unsigned short* __restrict__ A, const unsigned short* __restrict__ Bt,
    const float* __restrict__ bias, float* __restrict__ Cf,
    unsigned short* __restrict__ Cb, int M, int N, int K, int mode)
{
    __shared__ unsigned short As[TM * 64];
    __shared__ unsigned short Bs[TN * 64];
    gemm_body<TM, TN>(As, Bs, A, Bt, bias, Cf, Cb, M, N, K, mode,
                      blockIdx.x, blockIdx.y);
}

// Flat-grid GEMM with XCD-aware block swizzle: bid&7 = XCD (HW round-robin);
// each XCD gets a compact nx-col x rows_per_xcd-row region of the tile grid.
template <int TM, int TN>
__global__ __launch_bounds__(256) void gemm_xcd(
    const unsigned short* __restrict__ A, const unsigned short* __restrict__ Bt,
    const float* __restrict__ bias, float* __restrict__ Cf,
    unsigned short* __restrict__ Cb, int M, int N, int K, int mode,
    int nx, int rows_per_xcd)
{
    __shared__ unsigned short As[TM * 64];
    __shared__ unsigned short Bs[TN * 64];
    const int xcd = blockIdx.x & 7;
    const int idx = blockIdx.x >> 3;
    const int bx  = idx % nx;
    const int by  = xcd * rows_per_xcd + idx / nx;
    gemm_body<TM, TN>(As, Bs, A, Bt, bias, Cf, Cb, M, N, K, mode, bx, by);
}

// Two independent GEMMs (same tile config) in one flat-grid dispatch.
template <int TM, int TN>
__global__ __launch_bounds__(256) void gemm_dual(
    const unsigned short* __restrict__ A0, const unsigned short* __restrict__ B0,
    const float* __restrict__ bias0, unsigned short* __restrict__ C0,
    int M0, int N0, int K0, int mode0, int nb0, int nx0,
    const unsigned short* __restrict__ A1, const unsigned short* __restrict__ B1,
    const float* __restrict__ bias1, unsigned short* __restrict__ C1,
    int M1, int N1, int K1, int mode1, int nx1)
{
    __shared__ unsigned short As[TM * 64];
    __shared__ unsigned short Bs[TN * 64];
    const int bid = blockIdx.x;
    if (bid < nb0) {
        gemm_body<TM, TN>(As, Bs, A0, B0, bias0, nullptr, C0,
                          M0, N0, K0, mode0, bid % nx0, bid / nx0);
    } else {
        const int t = bid - nb0;
        gemm_body<TM, TN>(As, Bs, A1, B1, bias1, nullptr, C1,
                          M1, N1, K1, mode1, t % nx1, t / nx1);
    }
}

// ---------------------------------------------------------------------------
// MFMA flash attention v2. qk: [4096][2048] bf16 (q cols 0..1023, k 1024..),
// vt: [1024][4096] bf16 (row = h*64+d, col = b*2048+t), a: [4096][1024] fp32.
// ---------------------------------------------------------------------------
__global__ __launch_bounds__(256) void fattn_mfma(
    const unsigned short* __restrict__ qk,
    const unsigned short* __restrict__ vt,
    float* __restrict__ a)
{
    const int T = 2048, LDQK = 2048, LDVT = 4096, OUTC = 1024;
    const float cs = 0.04508422f;       // (1/32) * log2(e)

    __shared__ unsigned short Qs[2][64][32];
    __shared__ unsigned short Ks[2][64][32];
    __shared__ unsigned short Vs[2][64][32];
    __shared__ unsigned short Ps[4][16][72];

    const int tid  = threadIdx.x;
    const int lane = tid & 63;
    const int w    = tid >> 6;
    const int fm   = lane & 15;
    const int quad = lane >> 4;
    const int srow = lane >> 2;
    const int scol = (lane & 3) * 8;

    const int n  = blockIdx.x;
    const int lo = n & 255, hi = n >> 8;
    const int h  = ((lo >> 5) & 7) | ((hi & 1) << 3);
    const int b  = hi >> 1;
    const int qv = lo & 31;
    const int u  = ((qv & 1) << 4) | ((qv & 2) << 2) | (qv & 4) |
                   ((qv & 8) >> 2) | ((qv & 16) >> 4);
    const int qb = (hi & 1) ? (31 - u) : u;
    const int q0 = qb * 64;

    const size_t rowbase = (size_t)b * T;

#pragma unroll
    for (int i = 0; i < 2; ++i) {
        const int c  = w * 2 + i;
        const int kh = c & 1, rg = c >> 1;
        const unsigned short* src = qk + (rowbase + q0 + rg * 16 + srow) * LDQK
                                       + h * 64 + kh * 32 + scol;
        __builtin_amdgcn_global_load_lds(
            (const __attribute__((address_space(1))) void*)src,
            (__attribute__((address_space(3))) void*)&Qs[kh][rg * 16][0], 16, 0, 0);
    }
    __syncthreads();
    short8 qf0 = *(const short8*)&Qs[0][w * 16 + fm][quad * 8];
    short8 qf1 = *(const short8*)&Qs[1][w * 16 + fm][quad * 8];

    short8 ones;
#pragma unroll
    for (int i = 0; i < 8; ++i) ones[i] = (short)0x3F80;   // bf16 1.0

    f32x4 o[4] = {};
    f32x4 lacc = {};

    const int qglob = q0 + w * 16 + fm;

    for (int jt = 0; jt <= qb; ++jt) {
        const int j0 = jt * 64;
        __syncthreads();
#pragma unroll
        for (int i = 0; i < 2; ++i) {
            const int c  = w * 2 + i;
            const int kh = c & 1, rg = c >> 1;
            const unsigned short* ksrc = qk + (rowbase + j0 + rg * 16 + srow) * LDQK
                                            + 1024 + h * 64 + kh * 32 + scol;
            __builtin_amdgcn_global_load_lds(
                (const __attribute__((address_space(1))) void*)ksrc,
                (__attribute__((address_space(3))) void*)&Ks[kh][rg * 16][0], 16, 0, 0);
            const unsigned short* vsrc = vt + (size_t)(h * 64 + rg * 16 + srow) * LDVT
                                            + rowbase + j0 + kh * 32 + scol;
            __builtin_amdgcn_global_load_lds(
                (const __attribute__((address_space(1))) void*)vsrc,
                (__attribute__((address_space(3))) void*)&Vs[kh][rg * 16][0], 16, 0, 0);
        }
        __syncthreads();

        // S^T = K . Q^T
        f32x4 s[4];
#pragma unroll
        for (int j = 0; j < 4; ++j) {
            short8 k0 = *(const short8*)&Ks[0][j * 16 + fm][quad * 8];
            short8 k1 = *(const short8*)&Ks[1][j * 16 + fm][quad * 8];
            f32x4 acc = {};
            acc = __builtin_amdgcn_mfma_f32_16x16x32_bf16(k0, qf0, acc, 0, 0, 0);
            acc = __builtin_amdgcn_mfma_f32_16x16x32_bf16(k1, qf1, acc, 0, 0, 0);
            s[j] = acc;
        }

        if (jt == qb) {
#pragma unroll
            for (int j = 0; j < 4; ++j) {
                const int kbase = j0 + j * 16 + quad * 4;
#pragma unroll
                for (int r = 0; r < 4; ++r) {
                    const float e = exp2f(s[j][r] * cs);
                    s[j][r] = (kbase + r > qglob) ? 0.f : e;
                }
            }
        } else {
#pragma unroll
            for (int j = 0; j < 4; ++j)
#pragma unroll
                for (int r = 0; r < 4; ++r)
                    s[j][r] = exp2f(s[j][r] * cs);
        }

#pragma unroll
        for (int j = 0; j < 4; ++j) {
            const unsigned d0 = (unsigned)f2bf(s[j][0]) | ((unsigned)f2bf(s[j][1]) << 16);
            const unsigned d1 = (unsigned)f2bf(s[j][2]) | ((unsigned)f2bf(s[j][3]) << 16);
            *(uint2*)&Ps[w][fm][j * 16 + quad * 4] = make_uint2(d0, d1);
        }
        short8 pf0 = *(const short8*)&Ps[w][fm][quad * 8];
        short8 pf1 = *(const short8*)&Ps[w][fm][32 + quad * 8];

#pragma unroll
        for (int jd = 0; jd < 4; ++jd) {
            short8 v0 = *(const short8*)&Vs[0][jd * 16 + fm][quad * 8];
            short8 v1 = *(const short8*)&Vs[1][jd * 16 + fm][quad * 8];
            o[jd] = __builtin_amdgcn_mfma_f32_16x16x32_bf16(pf0, v0, o[jd], 0, 0, 0);
            o[jd] = __builtin_amdgcn_mfma_f32_16x16x32_bf16(pf1, v1, o[jd], 0, 0, 0);
        }
        lacc = __builtin_amdgcn_mfma_f32_16x16x32_bf16(pf0, ones, lacc, 0, 0, 0);
        lacc = __builtin_amdgcn_mfma_f32_16x16x32_bf16(pf1, ones, lacc, 0, 0, 0);
    }

    const size_t orow = rowbase + q0 + w * 16 + quad * 4;
#pragma unroll
    for (int r = 0; r < 4; ++r) {
        const float inv = 1.0f / lacc[r];
#pragma unroll
        for (int jd = 0; jd < 4; ++jd)
            a[(orow + r) * OUTC + h * 64 + jd * 16 + fm] = o[jd][r] * inv;
    }
}

// out = in + LayerNorm(in)*w. bf16_out=1 -> write bf16 to outb, else fp32 outf.
__global__ __launch_bounds__(256) void add_ln_kernel(
    const float* __restrict__ in, const float* __restrict__ w,
    float* __restrict__ outf, unsigned short* __restrict__ outb, int bf16_out)
{
    const int C = 1024;
    const int row = blockIdx.x;
    const int tid = threadIdx.x;

    __shared__ float red[256];

    const float* x = in + (size_t)row * C;
    float4 xv = *(const float4*)(x + tid * 4);

    red[tid] = xv.x + xv.y + xv.z + xv.w;
    __syncthreads();
    for (int off = 128; off > 0; off >>= 1) {
        if (tid < off) red[tid] += red[tid + off];
        __syncthreads();
    }
    const float mu = red[0] * (1.0f / 1024.0f);
    __syncthreads();

    float dx = xv.x - mu, dy = xv.y - mu, dz = xv.z - mu, dw = xv.w - mu;
    red[tid] = dx * dx + dy * dy + dz * dz + dw * dw;
    __syncthreads();
    for (int off = 128; off > 0; off >>= 1) {
        if (tid < off) red[tid] += red[tid + off];
        __syncthreads();
    }
    const float rstd = rsqrtf(red[0] * (1.0f / 1024.0f) + 1e-5f);

    float4 wv = *(const float4*)(w + tid * 4);
    float ox = xv.x + dx * rstd * wv.x;
    float oy = xv.y + dy * rstd * wv.y;
    float oz = xv.z + dz * rstd * wv.z;
    float ow = xv.w + dw * rstd * wv.w;
    if (bf16_out) {
        ushort4 o4;
        o4.x = f2bf(ox); o4.y = f2bf(oy); o4.z = f2bf(oz); o4.w = f2bf(ow);
        *(ushort4*)(outb + (size_t)row * C + tid * 4) = o4;
    } else {
        *(float4*)(outf + (size_t)row * C + tid * 4) = make_float4(ox, oy, oz, ow);
    }
}

extern "C" void kernel_launch(void* const* d_in, const int* in_sizes, int n_in,
                              void* d_out, int out_size, void* d_ws, size_t ws_size,
                              hipStream_t stream)
{
    const float* x    = (const float*)d_in[0];
    const float* Wq   = (const float*)d_in[1];
    const float* bq   = (const float*)d_in[2];
    const float* Wk   = (const float*)d_in[3];
    const float* bk   = (const float*)d_in[4];
    const float* Wv   = (const float*)d_in[5];
    const float* bv   = (const float*)d_in[6];
    const float* W1   = (const float*)d_in[7];
    const float* b1   = (const float*)d_in[8];
    const float* W2   = (const float*)d_in[9];
    const float* b2   = (const float*)d_in[10];
    const float* ln_w = (const float*)d_in[11];
    float* out = (float*)d_out;
    char* ws = (char*)d_ws;

    const int B = 2, T = 2048, C = 1024, DFF = 4096;
    const int M = B * T;                 // 4096
    const size_t MB = 1048576;

    unsigned short* qk_bf = (unsigned short*)(ws);             // 16 MB [4096][2048]
    unsigned short* vt_bf = (unsigned short*)(ws + 16 * MB);   //  8 MB [1024][4096]
    float*          a     = (float*)(ws + 24 * MB);            // 16 MB [4096][1024]
    unsigned short* x_bf  = (unsigned short*)(ws + 40 * MB);   //  8 MB [4096][1024]
    unsigned short* Wqk_t = (unsigned short*)(ws + 48 * MB);   //  4 MB [2048][1024]
    unsigned short* Wvt   = (unsigned short*)(ws + 52 * MB);   //  2 MB [1024][1024]
    unsigned short* W1t   = (unsigned short*)(ws + 54 * MB);   //  8 MB [4096][1024]
    unsigned short* W2t   = (unsigned short*)(ws + 62 * MB);   //  8 MB [1024][4096]
    float*          bqk   = (float*)(ws + 70 * MB);            //  8 KB [2048]
    unsigned short* u_bf  = (unsigned short*)(ws + 71 * MB);   // 32 MB [4096][4096]
    unsigned short* h_bf  = x_bf;                              // reuse (x dead)
    float*          f     = (float*)(ws);                      // 16 MB, reuse qk

    dim3 blk(256);

    // One merged preprocessing dispatch.
    prep_kernel<<<dim3(15368), blk, 0, stream>>>(
        x, Wq, Wk, Wv, W1, W2, bq, bk,
        x_bf, Wqk_t, Wvt, W1t, W2t, bqk);

    // QK projection + V^T in one dual dispatch, both <64,64> BK=64.
    gemm_dual<64, 64><<<dim3(3072), blk, 0, stream>>>(
        x_bf, Wqk_t, bqk, qk_bf, M, 2 * C, C, 2, 2048, 32,
        Wvt, x_bf, bv, vt_bf, C, M, C, 3, 64);

    fattn_mfma<<<dim3(1024), blk, 0, stream>>>(qk_bf, vt_bf, a);

    add_ln_kernel<<<dim3(M), blk, 0, stream>>>(a, ln_w, nullptr, h_bf, 1);

    // FFN1: [4096,1024] x [1024,4096] -> relu -> bf16. <64,128> BK=64.
    gemm_bf16_mfma<64, 128><<<dim3(DFF / 128, M / 64), blk, 0, stream>>>(
        h_bf, W1t, b1, nullptr, u_bf, M, DFF, C, 1);

    // FFN2: [4096,4096] x [4096,1024] -> fp32. <128,64> BK=64, flat 512
    // blocks with XCD swizzle (grid 16 cols x 32 rows; 4 rows/XCD).
    gemm_xcd<128, 64><<<dim3(512), blk, 0, stream>>>(
        u_bf, W2t, b2, f, nullptr, M, C, DFF, 0, 16, 4);

    add_ln_kernel<<<dim3(M), blk, 0, stream>>>(f, ln_w, out, nullptr, 0);
}